// Round 16
// baseline (257.429 us; speedup 1.0000x reference)
//
#include <hip/hip_runtime.h>
#include <stdint.h>

// Problem constants
#define Bdim 4
#define Nseq 2048
#define Dmod 1024
#define Hn   16
#define HD   64
#define SCALE 0.03125f   // D^-0.5 = 1/32
#define L2E   1.44269504089f

typedef __attribute__((ext_vector_type(8))) short short8;
typedef __attribute__((ext_vector_type(8))) unsigned short ushort8;
typedef __attribute__((ext_vector_type(4))) float f32x4;
typedef __attribute__((ext_vector_type(16))) float f32x16;

typedef __attribute__((address_space(3))) uint32_t lds_u32;
typedef __attribute__((address_space(1))) const uint32_t glob_u32;

static __device__ __forceinline__ void gload_lds16(const unsigned short* g, unsigned short* l) {
    __builtin_amdgcn_global_load_lds((glob_u32*)(const void*)g, (lds_u32*)(void*)l, 16, 0, 0);
}

static __device__ __forceinline__ unsigned short f2bf(float f) {
    union { float f; uint32_t u; } v; v.f = f;
    uint32_t r = (v.u + 0x7FFFu + ((v.u >> 16) & 1u)) >> 16;
    return (unsigned short)r;
}

// ---------------- fused prep: cast x -> bf16, transpose+cast both weight matrices ----------------
__global__ __launch_bounds__(256) void prep_kernel(const float* __restrict__ x,
                                                   const float* __restrict__ w_qkv,
                                                   const float* __restrict__ w_proj,
                                                   unsigned short* __restrict__ xb,
                                                   unsigned short* __restrict__ wqkvT,
                                                   unsigned short* __restrict__ wprojT) {
    __shared__ unsigned short t[32][33];
    int bid = blockIdx.x, tid = threadIdx.x;
    if (bid < 2048) {
        const int n4 = (Bdim * Nseq * Dmod) / 4;
        int i = bid * 256 + tid;
        for (; i < n4; i += 2048 * 256) {
            float4 v = reinterpret_cast<const float4*>(x)[i];
            ushort4 o;
            o.x = f2bf(v.x); o.y = f2bf(v.y); o.z = f2bf(v.z); o.w = f2bf(v.w);
            reinterpret_cast<ushort4*>(xb)[i] = o;
        }
        return;
    }
    const float* in;
    unsigned short* out;
    int R, C, c0, r0;
    if (bid < 5120) {
        int lin = bid - 2048;
        in = w_qkv; out = wqkvT; R = 1024; C = 3072;
        c0 = (lin % 96) * 32; r0 = (lin / 96) * 32;
    } else {
        int lin = bid - 5120;
        in = w_proj; out = wprojT; R = 1024; C = 1024;
        c0 = (lin % 32) * 32; r0 = (lin / 32) * 32;
    }
    int tx = tid & 31, ty = tid >> 5;
#pragma unroll
    for (int i = 0; i < 4; ++i)
        t[ty + i*8][tx] = f2bf(in[(size_t)(r0 + ty + i*8) * C + c0 + tx]);
    __syncthreads();
#pragma unroll
    for (int i = 0; i < 4; ++i)
        out[(size_t)(c0 + ty + i*8) * R + r0 + tx] = t[tx][ty + i*8];
}

// ---------------- 256x256 GEMM, 8-phase counted-vmcnt schedule (m201-style) ----------------
// 8 waves (2m x 4n), per-wave 128x64 out. K=1024, BK=64 split into kk-halves of 32.
// LDS: per operand, ring of 4 half-slots x 16 KB (fragment-linear: 16 chunks of 1 KB).
// Phase (t,q): q = (kk<<1)|mihalf -> {stage 1 half of t+1; vmcnt(6) at q=0,2; barrier;
// ds_read frags; setprio(1); 16 MFMA; setprio(0); barrier}. Prefetch lead >= 3 phases.
template<bool OUT_BF16, bool BIAS, bool VSPLIT>
__global__ __launch_bounds__(512, 1) void gemm8p_kernel(const unsigned short* __restrict__ A,
                                                        const unsigned short* __restrict__ Bt,
                                                        void* __restrict__ Cv,
                                                        const float* __restrict__ bias,
                                                        unsigned short* __restrict__ vTp,
                                                        int N, int GX) {
    const int K = 1024;
    __shared__ unsigned short Aring[4 * 8192];   // 4 half-slots x 16 KB
    __shared__ unsigned short Bring[4 * 8192];

    int tid = threadIdx.x;
    int lane = tid & 63, w = tid >> 6;
    int lr = lane & 15, lg = lane >> 4;

    // XCD-chunked bijective remap (gridDim.x % 8 == 0)
    int lin = blockIdx.x;
    int cpx = gridDim.x >> 3;
    int nl = (lin & 7) * cpx + (lin >> 3);
    int m0 = (nl / GX) * 256, n0 = (nl % GX) * 256;

    int miG0 = (w >> 2) * 8;   // wave's first A-frag (of 16)
    int niG0 = (w & 3) * 4;    // wave's first B-frag (of 16)

    // staging: thread stages chunks c0 = w and c1 = 8+w of each half, lane-slot = lane (16 B)
    // chunk c holds rows X + c*16 + (lane&15), k-cols (lane>>4)*8 within the half's 32-k range
    const unsigned short* aS0 = A  + (size_t)(m0 + w * 16 + lr) * K + lg * 8;
    const unsigned short* aS1 = aS0 + (size_t)128 * K;
    const unsigned short* bS0 = Bt + (size_t)(n0 + w * 16 + lr) * K + lg * 8;
    const unsigned short* bS1 = bS0 + (size_t)128 * K;
    unsigned short* aD0 = Aring + w * 512;         // + slot*8192 (ushorts)
    unsigned short* aD1 = Aring + (8 + w) * 512;
    unsigned short* bD0 = Bring + w * 512;
    unsigned short* bD1 = Bring + (8 + w) * 512;

    f32x4 acc[8][4];
#pragma unroll
    for (int i = 0; i < 8; ++i)
#pragma unroll
        for (int j = 0; j < 4; ++j) acc[i][j] = (f32x4)0.f;

    // prologue: stage tile 0's halves in gate order A0, B0, A1, B1 (8 loads outstanding)
    gload_lds16(aS0, aD0);             gload_lds16(aS1, aD1);
    gload_lds16(bS0, bD0);             gload_lds16(bS1, bD1);
    gload_lds16(aS0 + 32, aD0 + 8192); gload_lds16(aS1 + 32, aD1 + 8192);
    gload_lds16(bS0 + 32, bD0 + 8192); gload_lds16(bS1 + 32, bD1 + 8192);

    for (int t = 0; t < 16; ++t) {
        int sR = (t & 1) * 2;                        // read slot pair {sR, sR+1}
        int sW = sR ^ 2;                             // write slot pair
        const char* A0p = (const char*)(Aring + sR * 8192);
        const char* B0p = (const char*)(Bring + sR * 8192);
        const char* A1p = A0p + 16384;
        const char* B1p = B0p + 16384;
        size_t ko = (size_t)(t + 1) * 64;
        short8 a[4], b[4];

        // ---- phase 0: stage A0(t+1); GATE kk0; B-kk0 + A-kk0 mi0..3; 16 MFMA ----
        if (t < 15) {
            gload_lds16(aS0 + ko, aD0 + sW * 8192);
            gload_lds16(aS1 + ko, aD1 + sW * 8192);
            asm volatile("s_waitcnt vmcnt(6)" ::: "memory");
        } else {
            asm volatile("s_waitcnt vmcnt(4)" ::: "memory");
        }
        __builtin_amdgcn_s_barrier();
#pragma unroll
        for (int ni = 0; ni < 4; ++ni)
            b[ni] = *reinterpret_cast<const short8*>(B0p + (niG0 + ni) * 1024 + lane * 16);
#pragma unroll
        for (int mi = 0; mi < 4; ++mi)
            a[mi] = *reinterpret_cast<const short8*>(A0p + (miG0 + mi) * 1024 + lane * 16);
        __builtin_amdgcn_s_setprio(1);
#pragma unroll
        for (int mi = 0; mi < 4; ++mi)
#pragma unroll
            for (int ni = 0; ni < 4; ++ni)
                acc[mi][ni] = __builtin_amdgcn_mfma_f32_16x16x32_bf16(a[mi], b[ni], acc[mi][ni], 0, 0, 0);
        __builtin_amdgcn_s_setprio(0);
        __builtin_amdgcn_s_barrier();

        // ---- phase 1: stage B0(t+1); A-kk0 mi4..7; 16 MFMA (b reused) ----
        if (t < 15) {
            gload_lds16(bS0 + ko, bD0 + sW * 8192);
            gload_lds16(bS1 + ko, bD1 + sW * 8192);
        }
#pragma unroll
        for (int mi = 0; mi < 4; ++mi)
            a[mi] = *reinterpret_cast<const short8*>(A0p + (miG0 + 4 + mi) * 1024 + lane * 16);
        __builtin_amdgcn_s_setprio(1);
#pragma unroll
        for (int mi = 0; mi < 4; ++mi)
#pragma unroll
            for (int ni = 0; ni < 4; ++ni)
                acc[4 + mi][ni] = __builtin_amdgcn_mfma_f32_16x16x32_bf16(a[mi], b[ni], acc[4 + mi][ni], 0, 0, 0);
        __builtin_amdgcn_s_setprio(0);
        __builtin_amdgcn_s_barrier();

        // ---- phase 2: stage A1(t+1); GATE kk1; B-kk1 + A-kk1 mi0..3; 16 MFMA ----
        if (t < 15) {
            gload_lds16(aS0 + ko + 32, aD0 + sW * 8192 + 8192);
            gload_lds16(aS1 + ko + 32, aD1 + sW * 8192 + 8192);
            asm volatile("s_waitcnt vmcnt(6)" ::: "memory");
        } else {
            asm volatile("s_waitcnt vmcnt(0)" ::: "memory");
        }
        __builtin_amdgcn_s_barrier();
#pragma unroll
        for (int ni = 0; ni < 4; ++ni)
            b[ni] = *reinterpret_cast<const short8*>(B1p + (niG0 + ni) * 1024 + lane * 16);
#pragma unroll
        for (int mi = 0; mi < 4; ++mi)
            a[mi] = *reinterpret_cast<const short8*>(A1p + (miG0 + mi) * 1024 + lane * 16);
        __builtin_amdgcn_s_setprio(1);
#pragma unroll
        for (int mi = 0; mi < 4; ++mi)
#pragma unroll
            for (int ni = 0; ni < 4; ++ni)
                acc[mi][ni] = __builtin_amdgcn_mfma_f32_16x16x32_bf16(a[mi], b[ni], acc[mi][ni], 0, 0, 0);
        __builtin_amdgcn_s_setprio(0);
        __builtin_amdgcn_s_barrier();

        // ---- phase 3: stage B1(t+1); A-kk1 mi4..7; 16 MFMA ----
        if (t < 15) {
            gload_lds16(bS0 + ko + 32, bD0 + sW * 8192 + 8192);
            gload_lds16(bS1 + ko + 32, bD1 + sW * 8192 + 8192);
        }
#pragma unroll
        for (int mi = 0; mi < 4; ++mi)
            a[mi] = *reinterpret_cast<const short8*>(A1p + (miG0 + 4 + mi) * 1024 + lane * 16);
        __builtin_amdgcn_s_setprio(1);
#pragma unroll
        for (int mi = 0; mi < 4; ++mi)
#pragma unroll
            for (int ni = 0; ni < 4; ++ni)
                acc[4 + mi][ni] = __builtin_amdgcn_mfma_f32_16x16x32_bf16(a[mi], b[ni], acc[4 + mi][ni], 0, 0, 0);
        __builtin_amdgcn_s_setprio(0);
        __builtin_amdgcn_s_barrier();
    }

    // ---- epilogue: C rows m0 + (w>>2)*128 + mi*16 + lg*4 + i, cols n0 + (w&3)*64 + ni*16 + lr ----
    int wr = (w >> 2) * 128, wc = (w & 3) * 64;
#pragma unroll
    for (int mi = 0; mi < 8; ++mi) {
#pragma unroll
        for (int ni = 0; ni < 4; ++ni) {
            int r = m0 + wr + mi*16 + lg*4;
            int c = n0 + wc + ni*16 + lr;
            if (VSPLIT && c >= 2048) {
                int cc = c - 2048;
                int bh = ((r >> 11) << 4) + (cc >> 6);
                int d = cc & 63;
                ushort4 o4;
                o4.x = f2bf(acc[mi][ni][0]);
                o4.y = f2bf(acc[mi][ni][1]);
                o4.z = f2bf(acc[mi][ni][2]);
                o4.w = f2bf(acc[mi][ni][3]);
                *reinterpret_cast<ushort4*>(vTp + ((size_t)(bh * 64 + d) * 2048) + (r & 2047)) = o4;
            } else {
                float bv = BIAS ? bias[c] : 0.f;
#pragma unroll
                for (int i = 0; i < 4; ++i) {
                    float v = acc[mi][ni][i] + bv;
                    if (OUT_BF16)
                        reinterpret_cast<unsigned short*>(Cv)[(size_t)(r + i) * N + c] = f2bf(v);
                    else
                        reinterpret_cast<float*>(Cv)[(size_t)(r + i) * N + c] = v;
                }
            }
        }
    }
}

// ---------------- flash attention (R7/R13 config, best measured) ----------------
__global__ __launch_bounds__(256, 2) void attn_kernel(const unsigned short* __restrict__ qkv,
                                                      const unsigned short* __restrict__ vT,
                                                      unsigned short* __restrict__ attn_o) {
    __shared__ unsigned short Kl[2 * 64 * 64];
    __shared__ unsigned short Vl[2 * 64 * 64];
    __shared__ unsigned short Pl[4 * 64 * 64];

    int w = blockIdx.x;
    int lid = (w & 7) * 64 + (w >> 3);
    int bh = lid >> 3, qb = lid & 7;
    int b = bh >> 4, h = bh & 15;

    int tid = threadIdx.x, lane = tid & 63, wv = tid >> 6;
    int lr = lane & 31, hi = lane >> 5;
    int q0 = qb * 256 + wv * 64;

    short8 qfA[4], qfB[4];
    {
        const unsigned short* qrowA = qkv + (size_t)(b * Nseq + q0 + lr) * 3072 + h * 64 + hi * 8;
        const unsigned short* qrowB = qrowA + (size_t)32 * 3072;
#pragma unroll
        for (int ks = 0; ks < 4; ++ks) {
            qfA[ks] = *reinterpret_cast<const short8*>(qrowA + ks * 16);
            qfB[ks] = *reinterpret_cast<const short8*>(qrowB + ks * 16);
        }
    }

    float mrunA = -1e30f, lrunA = 0.f, mrunB = -1e30f, lrunB = 0.f;
    f32x16 oA0 = (f32x16)0.f, oA1 = (f32x16)0.f, oB0 = (f32x16)0.f, oB1 = (f32x16)0.f;

    int sr = tid >> 2;
    const unsigned short* kg = qkv + (size_t)(b * Nseq + sr) * 3072 + 1024 + h * 64 + (tid & 3) * 16;
    const unsigned short* vg = vT + ((size_t)(bh * 64 + sr)) * Nseq + (tid & 3) * 16;
    int sb = (sr >> 5) * 4096 + (tid & 3) * 1024 + (sr & 31) * 16;
    char* Pw = (char*)Pl + wv * 8192 + lr * 16 + 8 * hi;
    char* Pr = (char*)Pl + wv * 8192 + lane * 16;

    {
        ushort8 a0 = *reinterpret_cast<const ushort8*>(kg);
        ushort8 a1 = *reinterpret_cast<const ushort8*>(kg + 8);
        ushort8 a2 = *reinterpret_cast<const ushort8*>(vg);
        ushort8 a3 = *reinterpret_cast<const ushort8*>(vg + 8);
        *reinterpret_cast<ushort8*>((char*)Kl + sb) = a0;
        *reinterpret_cast<ushort8*>((char*)Kl + sb + 512) = a1;
        *reinterpret_cast<ushort8*>((char*)Vl + sb) = a2;
        *reinterpret_cast<ushort8*>((char*)Vl + sb + 512) = a3;
    }
    ushort8 k0r = *reinterpret_cast<const ushort8*>(kg + (size_t)64 * 3072);
    ushort8 k1r = *reinterpret_cast<const ushort8*>(kg + (size_t)64 * 3072 + 8);
    ushort8 v0r = *reinterpret_cast<const ushort8*>(vg + 64);
    ushort8 v1r = *reinterpret_cast<const ushort8*>(vg + 72);

    int cur = 0;
    for (int jt = 0; jt < Nseq; jt += 64, cur ^= 1) {
        __syncthreads();
        int rb = cur * 8192, wb = rb ^ 8192;

        f32x16 sA0 = (f32x16)0.f, sA1 = (f32x16)0.f, sB0 = (f32x16)0.f, sB1 = (f32x16)0.f;
        __builtin_amdgcn_s_setprio(1);
#pragma unroll
        for (int ks = 0; ks < 4; ++ks) {
            short8 kf0 = *reinterpret_cast<const short8*>((char*)Kl + rb + ks*1024 + lane*16);
            short8 kf1 = *reinterpret_cast<const short8*>((char*)Kl + rb + 4096 + ks*1024 + lane*16);
            sA0 = __builtin_amdgcn_mfma_f32_32x32x16_bf16(kf0, qfA[ks], sA0, 0, 0, 0);
            sA1 = __builtin_amdgcn_mfma_f32_32x32x16_bf16(kf1, qfA[ks], sA1, 0, 0, 0);
            sB0 = __builtin_amdgcn_mfma_f32_32x32x16_bf16(kf0, qfB[ks], sB0, 0, 0, 0);
            sB1 = __builtin_amdgcn_mfma_f32_32x32x16_bf16(kf1, qfB[ks], sB1, 0, 0, 0);
        }
        __builtin_amdgcn_s_setprio(0);

        if (jt + 64 < Nseq) {
            *reinterpret_cast<ushort8*>((char*)Kl + wb + sb) = k0r;
            *reinterpret_cast<ushort8*>((char*)Kl + wb + sb + 512) = k1r;
            *reinterpret_cast<ushort8*>((char*)Vl + wb + sb) = v0r;
            *reinterpret_cast<ushort8*>((char*)Vl + wb + sb + 512) = v1r;
            int jn = jt + 128;
            if (jn < Nseq) {
                k0r = *reinterpret_cast<const ushort8*>(kg + (size_t)jn * 3072);
                k1r = *reinterpret_cast<const ushort8*>(kg + (size_t)jn * 3072 + 8);
                v0r = *reinterpret_cast<const ushort8*>(vg + jn);
                v1r = *reinterpret_cast<const ushort8*>(vg + jn + 8);
            }
        }

        float tA[16], tB[16];
#pragma unroll
        for (int i = 0; i < 16; ++i) { tA[i] = fmaxf(sA0[i], sA1[i]); tB[i] = fmaxf(sB0[i], sB1[i]); }
#pragma unroll
        for (int st = 8; st > 0; st >>= 1)
#pragma unroll
            for (int i = 0; i < st; ++i) { tA[i] = fmaxf(tA[i], tA[i + st]); tB[i] = fmaxf(tB[i], tB[i + st]); }
        float mlocA = fmaxf(tA[0], __shfl_xor(tA[0], 32)) * SCALE;
        float mlocB = fmaxf(tB[0], __shfl_xor(tB[0], 32)) * SCALE;

        if (!__all((mlocA <= mrunA + 8.f) && (mlocB <= mrunB + 8.f))) {
            float mnA = fmaxf(mrunA, mlocA);
            float fA = __builtin_amdgcn_exp2f((mrunA - mnA) * L2E);
            float mnB = fmaxf(mrunB, mlocB);
            float fB = __builtin_amdgcn_exp2f((mrunB - mnB) * L2E);
            lrunA *= fA; lrunB *= fB; mrunA = mnA; mrunB = mnB;
#pragma unroll
            for (int i = 0; i < 16; ++i) {
                oA0[i] *= fA; oA1[i] *= fA; oB0[i] *= fB; oB1[i] *= fB;
            }
        }

        const float c1 = SCALE * L2E;
        float c0A = -mrunA * L2E, c0B = -mrunB * L2E;
        float pA0[16], pA1[16], pB0[16], pB1[16];
#pragma unroll
        for (int i = 0; i < 16; ++i) {
            pA0[i] = __builtin_amdgcn_exp2f(fmaf(sA0[i], c1, c0A));
            pA1[i] = __builtin_amdgcn_exp2f(fmaf(sA1[i], c1, c0A));
            pB0[i] = __builtin_amdgcn_exp2f(fmaf(sB0[i], c1, c0B));
            pB1[i] = __builtin_amdgcn_exp2f(fmaf(sB1[i], c1, c0B));
        }

        uint32_t WA[16], WB[16];
#pragma unroll
        for (int m = 0; m < 8; ++m) {
            asm("v_cvt_pk_bf16_f32 %0, %1, %2" : "=v"(WA[m])   : "v"(pA0[2*m]), "v"(pA0[2*m+1]));
            asm("v_cvt_pk_bf16_f32 %0, %1, %2" : "=v"(WA[8+m]) : "v"(pA1[2*m]), "v"(pA1[2*m+1]));
            asm("v_cvt_pk_bf16_f32 %0, %1, %2" : "=v"(WB[m])   : "v"(pB0[2*m]), "v"(pB0[2*m+1]));
            asm("v_cvt_pk_bf16_f32 %0, %1, %2" : "=v"(WB[8+m]) : "v"(pB1[2*m]), "v"(pB1[2*m+1]));
        }
#pragma unroll
        for (int tt = 0; tt < 8; ++tt) {
            uint64_t valA = (uint64_t)WA[2*tt] | ((uint64_t)WA[2*tt+1] << 32);
            uint64_t valB = (uint64_t)WB[2*tt] | ((uint64_t)WB[2*tt+1] << 32);
            char* pa = Pw + (tt >> 1) * 1024 + (tt & 1) * 512;
            *reinterpret_cast<uint64_t*>(pa) = valA;
            *reinterpret_cast<uint64_t*>(pa + 4096) = valB;
        }

        float aA[16], aB[16];
#pragma unroll
        for (int i = 0; i < 16; ++i) { aA[i] = pA0[i] + pA1[i]; aB[i] = pB0[i] + pB1[i]; }
#pragma unroll
        for (int st = 8; st > 0; st >>= 1)
#pragma unroll
            for (int i = 0; i < st; ++i) { aA[i] += aA[i + st]; aB[i] += aB[i + st]; }
        lrunA += aA[0] + __shfl_xor(aA[0], 32);
        lrunB += aB[0] + __shfl_xor(aB[0], 32);

        __builtin_amdgcn_s_setprio(1);
#pragma unroll
        for (int ks4 = 0; ks4 < 4; ++ks4) {
            short8 vf0 = *reinterpret_cast<const short8*>((char*)Vl + rb + ks4*1024 + lane*16);
            short8 vf1 = *reinterpret_cast<const short8*>((char*)Vl + rb + 4096 + ks4*1024 + lane*16);
            short8 pfA = *reinterpret_cast<const short8*>(Pr + ks4*1024);
            short8 pfB = *reinterpret_cast<const short8*>(Pr + 4096 + ks4*1024);
            oA0 = __builtin_amdgcn_mfma_f32_32x32x16_bf16(vf0, pfA, oA0, 0, 0, 0);
            oA1 = __builtin_amdgcn_mfma_f32_32x32x16_bf16(vf1, pfA, oA1, 0, 0, 0);
            oB0 = __builtin_amdgcn_mfma_f32_32x32x16_bf16(vf0, pfB, oB0, 0, 0, 0);
            oB1 = __builtin_amdgcn_mfma_f32_32x32x16_bf16(vf1, pfB, oB1, 0, 0, 0);
        }
        __builtin_amdgcn_s_setprio(0);
    }

    float invA = 1.f / lrunA, invB = 1.f / lrunB;
    unsigned short* orowA = attn_o + (size_t)(b * Nseq + q0 + lr) * Dmod + h * 64;
    unsigned short* orowB = attn_o + (size_t)(b * Nseq + q0 + 32 + lr) * Dmod + h * 64;
#pragma unroll
    for (int db = 0; db < 2; ++db)
#pragma unroll
        for (int g = 0; g < 4; ++g) {
            int d = db * 32 + 8 * g + 4 * hi;
            ushort4 o4;
            o4.x = f2bf((db ? oA1[4*g+0] : oA0[4*g+0]) * invA);
            o4.y = f2bf((db ? oA1[4*g+1] : oA0[4*g+1]) * invA);
            o4.z = f2bf((db ? oA1[4*g+2] : oA0[4*g+2]) * invA);
            o4.w = f2bf((db ? oA1[4*g+3] : oA0[4*g+3]) * invA);
            *reinterpret_cast<ushort4*>(orowA + d) = o4;
            o4.x = f2bf((db ? oB1[4*g+0] : oB0[4*g+0]) * invB);
            o4.y = f2bf((db ? oB1[4*g+1] : oB0[4*g+1]) * invB);
            o4.z = f2bf((db ? oB1[4*g+2] : oB0[4*g+2]) * invB);
            o4.w = f2bf((db ? oB1[4*g+3] : oB0[4*g+3]) * invB);
            *reinterpret_cast<ushort4*>(orowB + d) = o4;
        }
}

// ---------------- launch ----------------
extern "C" void kernel_launch(void* const* d_in, const int* in_sizes, int n_in,
                              void* d_out, int out_size, void* d_ws, size_t ws_size,
                              hipStream_t stream) {
    const float* x      = (const float*)d_in[0];
    const float* w_qkv  = (const float*)d_in[1];
    const float* w_proj = (const float*)d_in[2];
    const float* b_proj = (const float*)d_in[3];
    float* out = (float*)d_out;
    char* ws = (char*)d_ws;

    unsigned short* qkv    = (unsigned short*)(ws);               // 50331648 B (V third unused)
    unsigned short* vT     = (unsigned short*)(ws + 50331648);    // 16777216 B
    unsigned short* xb     = (unsigned short*)(ws + 67108864);    // 16777216 B (reused as attn_o)
    unsigned short* attn_o = xb;
    unsigned short* wqkvT  = (unsigned short*)(ws + 83886080);    // 6291456 B
    unsigned short* wprojT = (unsigned short*)(ws + 90177536);    // 2097152 B

    prep_kernel<<<6144, 256, 0, stream>>>(x, w_qkv, w_proj, xb, wqkvT, wprojT);
    // GEMM1: qkv = xb @ wqkvT^T, V third -> vT; 384 blocks of 256x256
    gemm8p_kernel<true, false, true><<<384, 512, 0, stream>>>(
        xb, wqkvT, qkv, nullptr, vT, 3072, 12);
    attn_kernel<<<512, 256, 0, stream>>>(qkv, vT, attn_o);
    // GEMM2: out = attn_o @ wprojT^T + bias; 128 blocks of 256x256
    gemm8p_kernel<false, true, false><<<128, 512, 0, stream>>>(
        attn_o, wprojT, out, b_proj, nullptr, 1024, 4);
}

// Round 17
// 220.415 us; speedup vs baseline: 1.1679x; 1.1679x over previous
//
#include <hip/hip_runtime.h>
#include <stdint.h>

// Problem constants
#define Bdim 4
#define Nseq 2048
#define Dmod 1024
#define Hn   16
#define HD   64
#define SCALE 0.03125f   // D^-0.5 = 1/32
#define L2E   1.44269504089f

typedef __attribute__((ext_vector_type(8))) short short8;
typedef __attribute__((ext_vector_type(8))) unsigned short ushort8;
typedef __attribute__((ext_vector_type(4))) float f32x4;
typedef __attribute__((ext_vector_type(16))) float f32x16;

typedef __attribute__((address_space(3))) uint32_t lds_u32;
typedef __attribute__((address_space(1))) const uint32_t glob_u32;

static __device__ __forceinline__ void gload_lds16(const unsigned short* g, unsigned short* l) {
    __builtin_amdgcn_global_load_lds((glob_u32*)(const void*)g, (lds_u32*)(void*)l, 16, 0, 0);
}

static __device__ __forceinline__ unsigned short f2bf(float f) {
    union { float f; uint32_t u; } v; v.f = f;
    uint32_t r = (v.u + 0x7FFFu + ((v.u >> 16) & 1u)) >> 16;
    return (unsigned short)r;
}

// ---------------- fused prep: cast x -> bf16, transpose+cast both weight matrices ----------------
// blocks [0,2048): cast x (grid-stride float4); [2048,5120): w_qkv^T; [5120,6144): w_proj^T
__global__ __launch_bounds__(256) void prep_kernel(const float* __restrict__ x,
                                                   const float* __restrict__ w_qkv,
                                                   const float* __restrict__ w_proj,
                                                   unsigned short* __restrict__ xb,
                                                   unsigned short* __restrict__ wqkvT,
                                                   unsigned short* __restrict__ wprojT) {
    __shared__ unsigned short t[32][33];
    int bid = blockIdx.x, tid = threadIdx.x;
    if (bid < 2048) {
        const int n4 = (Bdim * Nseq * Dmod) / 4;
        int i = bid * 256 + tid;
        for (; i < n4; i += 2048 * 256) {
            float4 v = reinterpret_cast<const float4*>(x)[i];
            ushort4 o;
            o.x = f2bf(v.x); o.y = f2bf(v.y); o.z = f2bf(v.z); o.w = f2bf(v.w);
            reinterpret_cast<ushort4*>(xb)[i] = o;
        }
        return;
    }
    const float* in;
    unsigned short* out;
    int R, C, c0, r0;
    if (bid < 5120) {
        int lin = bid - 2048;            // 3072 blocks: 96 x 32
        in = w_qkv; out = wqkvT; R = 1024; C = 3072;
        c0 = (lin % 96) * 32; r0 = (lin / 96) * 32;
    } else {
        int lin = bid - 5120;            // 1024 blocks: 32 x 32
        in = w_proj; out = wprojT; R = 1024; C = 1024;
        c0 = (lin % 32) * 32; r0 = (lin / 32) * 32;
    }
    int tx = tid & 31, ty = tid >> 5;    // 32 x 8, same mapping as old dim3(32,8)
#pragma unroll
    for (int i = 0; i < 4; ++i)
        t[ty + i*8][tx] = f2bf(in[(size_t)(r0 + ty + i*8) * C + c0 + tx]);
    __syncthreads();
#pragma unroll
    for (int i = 0; i < 4; ++i)
        out[(size_t)(c0 + ty + i*8) * R + r0 + tx] = t[tx][ty + i*8];
}

// ---------------- bf16 GEMM (m97 structure + XCD remap + optional V->vT redirect) ----------------
template<bool OUT_BF16, bool BIAS, bool VSPLIT>
__global__ __launch_bounds__(256) void gemm_bt_kernel(const unsigned short* __restrict__ A,
                                                      const unsigned short* __restrict__ Bt,
                                                      void* __restrict__ Cv,
                                                      const float* __restrict__ bias,
                                                      unsigned short* __restrict__ vTp,
                                                      int M, int N, int K) {
    __shared__ unsigned short Al[128 * 64];
    __shared__ unsigned short Bl[128 * 64];
    int tid = threadIdx.x;
    int lane = tid & 63, wv = tid >> 6;
    int wr = (wv >> 1) * 64, wc = (wv & 1) * 64;
    int lr = lane & 15, lg = lane >> 4, lk = lg * 8;

    int gx = gridDim.x;
    int lin = blockIdx.y * gx + blockIdx.x;
    int cpx = (gx * gridDim.y) >> 3;
    int nl = (lin & 7) * cpx + (lin >> 3);
    int m0 = (nl / gx) * 128, n0 = (nl % gx) * 128;

    int srow = wv * 8 + (lane >> 3);
    int scol = (lane & 7) * 8;
    const unsigned short* ag = A  + (size_t)(m0 + srow) * K + scol;
    const unsigned short* bg = Bt + (size_t)(n0 + srow) * K + scol;
    unsigned short* la = Al + wv * 512;
    unsigned short* lb = Bl + wv * 512;

    f32x4 acc[4][4];
#pragma unroll
    for (int i = 0; i < 4; ++i)
#pragma unroll
        for (int j = 0; j < 4; ++j) acc[i][j] = (f32x4)0.f;

    for (int k0 = 0; k0 < K; k0 += 64) {
        __syncthreads();
#pragma unroll
        for (int i = 0; i < 4; ++i) {
            gload_lds16(ag + (size_t)i * 32 * K + k0, la + i * 2048);
            gload_lds16(bg + (size_t)i * 32 * K + k0, lb + i * 2048);
        }
        __syncthreads();
#pragma unroll
        for (int ks = 0; ks < 2; ++ks) {
            short8 a[4], b[4];
#pragma unroll
            for (int mi = 0; mi < 4; ++mi)
                a[mi] = *reinterpret_cast<const short8*>(Al + (wr + mi*16 + lr) * 64 + ks*32 + lk);
#pragma unroll
            for (int nj = 0; nj < 4; ++nj)
                b[nj] = *reinterpret_cast<const short8*>(Bl + (wc + nj*16 + lr) * 64 + ks*32 + lk);
#pragma unroll
            for (int mi = 0; mi < 4; ++mi)
#pragma unroll
                for (int nj = 0; nj < 4; ++nj)
                    acc[mi][nj] = __builtin_amdgcn_mfma_f32_16x16x32_bf16(a[mi], b[nj], acc[mi][nj], 0, 0, 0);
        }
    }
#pragma unroll
    for (int mi = 0; mi < 4; ++mi) {
#pragma unroll
        for (int nj = 0; nj < 4; ++nj) {
            int r = m0 + wr + mi*16 + lg*4;
            int c = n0 + wc + nj*16 + lr;
            if (VSPLIT && c >= 2048) {
                int cc = c - 2048;
                int bh = ((r >> 11) << 4) + (cc >> 6);
                int d = cc & 63;
                ushort4 o4;
                o4.x = f2bf(acc[mi][nj][0]);
                o4.y = f2bf(acc[mi][nj][1]);
                o4.z = f2bf(acc[mi][nj][2]);
                o4.w = f2bf(acc[mi][nj][3]);
                *reinterpret_cast<ushort4*>(vTp + ((size_t)(bh * 64 + d) * 2048) + (r & 2047)) = o4;
            } else {
                float bv = BIAS ? bias[c] : 0.f;
#pragma unroll
                for (int i = 0; i < 4; ++i) {
                    float v = acc[mi][nj][i] + bv;
                    if (OUT_BF16)
                        reinterpret_cast<unsigned short*>(Cv)[(size_t)(r + i) * N + c] = f2bf(v);
                    else
                        reinterpret_cast<float*>(Cv)[(size_t)(r + i) * N + c] = v;
                }
            }
        }
    }
}

// ---------------- flash attention (R7 config, best measured): 64 q/wave, dbuf K/V, ----------------
// fragment-linear LDS (contiguous 1KB fragment blocks), P via per-wave LDS tile,
// defer-max (T13), setprio (T5), reg-staged K/V with next-tile loads issued under compute.
__global__ __launch_bounds__(256, 2) void attn_kernel(const unsigned short* __restrict__ qkv,
                                                      const unsigned short* __restrict__ vT,
                                                      unsigned short* __restrict__ attn_o) {
    __shared__ unsigned short Kl[2 * 64 * 64];   // double-buffered, 8192 B each
    __shared__ unsigned short Vl[2 * 64 * 64];
    __shared__ unsigned short Pl[4 * 64 * 64];   // per-wave 8192 B (subtile A, then B)

    // bijective XCD-chunked swizzle: 512 blocks = 8 XCDs x 64
    int w = blockIdx.x;
    int lid = (w & 7) * 64 + (w >> 3);
    int bh = lid >> 3, qb = lid & 7;
    int b = bh >> 4, h = bh & 15;

    int tid = threadIdx.x, lane = tid & 63, wv = tid >> 6;
    int lr = lane & 31, hi = lane >> 5;
    int q0 = qb * 256 + wv * 64;

    // Q b-frags for both subtiles: qf[ks] elem j = Q[q][ks*16 + hi*8 + j]  (assumed map)
    short8 qfA[4], qfB[4];
    {
        const unsigned short* qrowA = qkv + (size_t)(b * Nseq + q0 + lr) * 3072 + h * 64 + hi * 8;
        const unsigned short* qrowB = qrowA + (size_t)32 * 3072;
#pragma unroll
        for (int ks = 0; ks < 4; ++ks) {
            qfA[ks] = *reinterpret_cast<const short8*>(qrowA + ks * 16);
            qfB[ks] = *reinterpret_cast<const short8*>(qrowB + ks * 16);
        }
    }

    float mrunA = -1e30f, lrunA = 0.f, mrunB = -1e30f, lrunB = 0.f;
    f32x16 oA0 = (f32x16)0.f, oA1 = (f32x16)0.f, oB0 = (f32x16)0.f, oB1 = (f32x16)0.f;

    // staging: thread t covers K row sr (kv), d block (tid&3)*16  /  V row sr (d), kv block (tid&3)*16
    int sr = tid >> 2;
    const unsigned short* kg = qkv + (size_t)(b * Nseq + sr) * 3072 + 1024 + h * 64 + (tid & 3) * 16;
    const unsigned short* vg = vT + ((size_t)(bh * 64 + sr)) * Nseq + (tid & 3) * 16;
    // fragment-linear staging offset (chunk0; chunk1 = +512): same formula for K and V tiles
    int sb = (sr >> 5) * 4096 + (tid & 3) * 1024 + (sr & 31) * 16;
    char* Pw = (char*)Pl + wv * 8192 + lr * 16 + 8 * hi;   // + (t>>1)*1024 + (t&1)*512 per b64
    char* Pr = (char*)Pl + wv * 8192 + lane * 16;          // + ks4*1024 (subtile A), +4096 (B)

    // prologue: stage tile 0 into buffer 0
    {
        ushort8 a0 = *reinterpret_cast<const ushort8*>(kg);
        ushort8 a1 = *reinterpret_cast<const ushort8*>(kg + 8);
        ushort8 a2 = *reinterpret_cast<const ushort8*>(vg);
        ushort8 a3 = *reinterpret_cast<const ushort8*>(vg + 8);
        *reinterpret_cast<ushort8*>((char*)Kl + sb) = a0;
        *reinterpret_cast<ushort8*>((char*)Kl + sb + 512) = a1;
        *reinterpret_cast<ushort8*>((char*)Vl + sb) = a2;
        *reinterpret_cast<ushort8*>((char*)Vl + sb + 512) = a3;
    }
    // issue tile 1 loads
    ushort8 k0r = *reinterpret_cast<const ushort8*>(kg + (size_t)64 * 3072);
    ushort8 k1r = *reinterpret_cast<const ushort8*>(kg + (size_t)64 * 3072 + 8);
    ushort8 v0r = *reinterpret_cast<const ushort8*>(vg + 64);
    ushort8 v1r = *reinterpret_cast<const ushort8*>(vg + 72);

    int cur = 0;
    for (int jt = 0; jt < Nseq; jt += 64, cur ^= 1) {
        __syncthreads();   // buf[cur] fully written by all waves
        int rb = cur * 8192, wb = rb ^ 8192;

        // ---- S^T = K · Q^T : kf reads are contiguous 1KB blocks, conflict-free ----
        f32x16 sA0 = (f32x16)0.f, sA1 = (f32x16)0.f, sB0 = (f32x16)0.f, sB1 = (f32x16)0.f;
        __builtin_amdgcn_s_setprio(1);
#pragma unroll
        for (int ks = 0; ks < 4; ++ks) {
            short8 kf0 = *reinterpret_cast<const short8*>((char*)Kl + rb + ks*1024 + lane*16);
            short8 kf1 = *reinterpret_cast<const short8*>((char*)Kl + rb + 4096 + ks*1024 + lane*16);
            sA0 = __builtin_amdgcn_mfma_f32_32x32x16_bf16(kf0, qfA[ks], sA0, 0, 0, 0);
            sA1 = __builtin_amdgcn_mfma_f32_32x32x16_bf16(kf1, qfA[ks], sA1, 0, 0, 0);
            sB0 = __builtin_amdgcn_mfma_f32_32x32x16_bf16(kf0, qfB[ks], sB0, 0, 0, 0);
            sB1 = __builtin_amdgcn_mfma_f32_32x32x16_bf16(kf1, qfB[ks], sB1, 0, 0, 0);
        }
        __builtin_amdgcn_s_setprio(0);

        // ---- stage tile t+1 into buf[cur^1] (off critical path) ----
        if (jt + 64 < Nseq) {
            *reinterpret_cast<ushort8*>((char*)Kl + wb + sb) = k0r;
            *reinterpret_cast<ushort8*>((char*)Kl + wb + sb + 512) = k1r;
            *reinterpret_cast<ushort8*>((char*)Vl + wb + sb) = v0r;
            *reinterpret_cast<ushort8*>((char*)Vl + wb + sb + 512) = v1r;
            int jn = jt + 128;
            if (jn < Nseq) {
                k0r = *reinterpret_cast<const ushort8*>(kg + (size_t)jn * 3072);
                k1r = *reinterpret_cast<const ushort8*>(kg + (size_t)jn * 3072 + 8);
                v0r = *reinterpret_cast<const ushort8*>(vg + jn);
                v1r = *reinterpret_cast<const ushort8*>(vg + jn + 8);
            }
        }

        // ---- per-lane tile max for both subtiles ----
        float tA[16], tB[16];
#pragma unroll
        for (int i = 0; i < 16; ++i) { tA[i] = fmaxf(sA0[i], sA1[i]); tB[i] = fmaxf(sB0[i], sB1[i]); }
#pragma unroll
        for (int st = 8; st > 0; st >>= 1)
#pragma unroll
            for (int i = 0; i < st; ++i) { tA[i] = fmaxf(tA[i], tA[i + st]); tB[i] = fmaxf(tB[i], tB[i + st]); }
        float mlocA = fmaxf(tA[0], __shfl_xor(tA[0], 32)) * SCALE;
        float mlocB = fmaxf(tB[0], __shfl_xor(tB[0], 32)) * SCALE;

        // ---- defer-max (T13): rescale only when max grew > 8 ----
        if (!__all((mlocA <= mrunA + 8.f) && (mlocB <= mrunB + 8.f))) {
            float mnA = fmaxf(mrunA, mlocA);
            float fA = __builtin_amdgcn_exp2f((mrunA - mnA) * L2E);
            float mnB = fmaxf(mrunB, mlocB);
            float fB = __builtin_amdgcn_exp2f((mrunB - mnB) * L2E);
            lrunA *= fA; lrunB *= fB; mrunA = mnA; mrunB = mnB;
#pragma unroll
            for (int i = 0; i < 16; ++i) {
                oA0[i] *= fA; oA1[i] *= fA; oB0[i] *= fB; oB1[i] *= fB;
            }
        }

        // ---- P = exp2(s*c1 + c0) ----
        const float c1 = SCALE * L2E;
        float c0A = -mrunA * L2E, c0B = -mrunB * L2E;
        float pA0[16], pA1[16], pB0[16], pB1[16];
#pragma unroll
        for (int i = 0; i < 16; ++i) {
            pA0[i] = __builtin_amdgcn_exp2f(fmaf(sA0[i], c1, c0A));
            pA1[i] = __builtin_amdgcn_exp2f(fmaf(sA1[i], c1, c0A));
            pB0[i] = __builtin_amdgcn_exp2f(fmaf(sB0[i], c1, c0B));
            pB1[i] = __builtin_amdgcn_exp2f(fmaf(sB1[i], c1, c0B));
        }

        // ---- pack + write P, fragment-linear b64 stores (conflict-free) ----
        uint32_t WA[16], WB[16];
#pragma unroll
        for (int m = 0; m < 8; ++m) {
            asm("v_cvt_pk_bf16_f32 %0, %1, %2" : "=v"(WA[m])   : "v"(pA0[2*m]), "v"(pA0[2*m+1]));
            asm("v_cvt_pk_bf16_f32 %0, %1, %2" : "=v"(WA[8+m]) : "v"(pA1[2*m]), "v"(pA1[2*m+1]));
            asm("v_cvt_pk_bf16_f32 %0, %1, %2" : "=v"(WB[m])   : "v"(pB0[2*m]), "v"(pB0[2*m+1]));
            asm("v_cvt_pk_bf16_f32 %0, %1, %2" : "=v"(WB[8+m]) : "v"(pB1[2*m]), "v"(pB1[2*m+1]));
        }
#pragma unroll
        for (int tt = 0; tt < 8; ++tt) {
            uint64_t valA = (uint64_t)WA[2*tt] | ((uint64_t)WA[2*tt+1] << 32);
            uint64_t valB = (uint64_t)WB[2*tt] | ((uint64_t)WB[2*tt+1] << 32);
            char* pa = Pw + (tt >> 1) * 1024 + (tt & 1) * 512;
            *reinterpret_cast<uint64_t*>(pa) = valA;
            *reinterpret_cast<uint64_t*>(pa + 4096) = valB;
        }

        float aA[16], aB[16];
#pragma unroll
        for (int i = 0; i < 16; ++i) { aA[i] = pA0[i] + pA1[i]; aB[i] = pB0[i] + pB1[i]; }
#pragma unroll
        for (int st = 8; st > 0; st >>= 1)
#pragma unroll
            for (int i = 0; i < st; ++i) { aA[i] += aA[i + st]; aB[i] += aB[i + st]; }
        lrunA += aA[0] + __shfl_xor(aA[0], 32);
        lrunB += aB[0] + __shfl_xor(aB[0], 32);

        // ---- O^T += V^T · P : all reads contiguous 1KB fragment blocks ----
        __builtin_amdgcn_s_setprio(1);
#pragma unroll
        for (int ks4 = 0; ks4 < 4; ++ks4) {
            short8 vf0 = *reinterpret_cast<const short8*>((char*)Vl + rb + ks4*1024 + lane*16);
            short8 vf1 = *reinterpret_cast<const short8*>((char*)Vl + rb + 4096 + ks4*1024 + lane*16);
            short8 pfA = *reinterpret_cast<const short8*>(Pr + ks4*1024);
            short8 pfB = *reinterpret_cast<const short8*>(Pr + 4096 + ks4*1024);
            oA0 = __builtin_amdgcn_mfma_f32_32x32x16_bf16(vf0, pfA, oA0, 0, 0, 0);
            oA1 = __builtin_amdgcn_mfma_f32_32x32x16_bf16(vf1, pfA, oA1, 0, 0, 0);
            oB0 = __builtin_amdgcn_mfma_f32_32x32x16_bf16(vf0, pfB, oB0, 0, 0, 0);
            oB1 = __builtin_amdgcn_mfma_f32_32x32x16_bf16(vf1, pfB, oB1, 0, 0, 0);
        }
        __builtin_amdgcn_s_setprio(0);
    }

    // ---- epilogue: O^T[d][q] -> attn_o[b*N + q][h*64 + d] ----
    float invA = 1.f / lrunA, invB = 1.f / lrunB;
    unsigned short* orowA = attn_o + (size_t)(b * Nseq + q0 + lr) * Dmod + h * 64;
    unsigned short* orowB = attn_o + (size_t)(b * Nseq + q0 + 32 + lr) * Dmod + h * 64;
#pragma unroll
    for (int db = 0; db < 2; ++db)
#pragma unroll
        for (int g = 0; g < 4; ++g) {
            int d = db * 32 + 8 * g + 4 * hi;
            ushort4 o4;
            o4.x = f2bf((db ? oA1[4*g+0] : oA0[4*g+0]) * invA);
            o4.y = f2bf((db ? oA1[4*g+1] : oA0[4*g+1]) * invA);
            o4.z = f2bf((db ? oA1[4*g+2] : oA0[4*g+2]) * invA);
            o4.w = f2bf((db ? oA1[4*g+3] : oA0[4*g+3]) * invA);
            *reinterpret_cast<ushort4*>(orowA + d) = o4;
            o4.x = f2bf((db ? oB1[4*g+0] : oB0[4*g+0]) * invB);
            o4.y = f2bf((db ? oB1[4*g+1] : oB0[4*g+1]) * invB);
            o4.z = f2bf((db ? oB1[4*g+2] : oB0[4*g+2]) * invB);
            o4.w = f2bf((db ? oB1[4*g+3] : oB0[4*g+3]) * invB);
            *reinterpret_cast<ushort4*>(orowB + d) = o4;
        }
}

// ---------------- launch ----------------
extern "C" void kernel_launch(void* const* d_in, const int* in_sizes, int n_in,
                              void* d_out, int out_size, void* d_ws, size_t ws_size,
                              hipStream_t stream) {
    const float* x      = (const float*)d_in[0];
    const float* w_qkv  = (const float*)d_in[1];
    const float* w_proj = (const float*)d_in[2];
    const float* b_proj = (const float*)d_in[3];
    float* out = (float*)d_out;
    char* ws = (char*)d_ws;

    unsigned short* qkv    = (unsigned short*)(ws);               // 50331648 B (V third unused)
    unsigned short* vT     = (unsigned short*)(ws + 50331648);    // 16777216 B
    unsigned short* xb     = (unsigned short*)(ws + 67108864);    // 16777216 B (reused as attn_o)
    unsigned short* attn_o = xb;
    unsigned short* wqkvT  = (unsigned short*)(ws + 83886080);    // 6291456 B
    unsigned short* wprojT = (unsigned short*)(ws + 90177536);    // 2097152 B

    prep_kernel<<<6144, 256, 0, stream>>>(x, w_qkv, w_proj, xb, wqkvT, wprojT);
    // qkv = x @ w_qkv; V columns redirected (transposed) into vT
    gemm_bt_kernel<true, false, true><<<dim3(3072/128, 8192/128), 256, 0, stream>>>(
        xb, wqkvT, qkv, nullptr, vT, Bdim*Nseq, 3*Dmod, Dmod);
    attn_kernel<<<512, 256, 0, stream>>>(qkv, vT, attn_o);
    gemm_bt_kernel<false, true, false><<<dim3(1024/128, 8192/128), 256, 0, stream>>>(
        attn_o, wprojT, out, b_proj, nullptr, Bdim*Nseq, Dmod, Dmod);
}